// Round 10
// baseline (3277.865 us; speedup 1.0000x reference)
//
#include <hip/hip_runtime.h>
#include <hip/hip_fp16.h>

#define DEVINL __device__ __forceinline__

constexpr int B = 256, S = 512;
constexpr int H0 = 64, H1 = 128, H2 = 256;

typedef _Float16 f16x8 __attribute__((ext_vector_type(8)));
typedef float f32x4 __attribute__((ext_vector_type(4)));
typedef _Float16 h2v __attribute__((ext_vector_type(2)));

DEVINL float fexp2(float x) { return __builtin_amdgcn_exp2f(x); }
DEVINL float frcp(float x) { return __builtin_amdgcn_rcpf(x); }
DEVINL float fsig(float x) { return frcp(1.f + fexp2(-1.44269504088896f * x)); }
DEVINL float ftanh_(float x) { return 1.f - 2.f * frcp(1.f + fexp2(2.88539008177793f * x)); }
DEVINL h2v as_h2(unsigned u) { union { unsigned u; h2v h; } x; x.u = u; return x.h; }
DEVINL float fdot2(unsigned a, unsigned b, float c) {
  return __builtin_amdgcn_fdot2(as_h2(a), as_h2(b), c, false);
}
union FU { uint4 u; f16x8 h; };
DEVINL f16x8 as_f16x8(uint4 u) { FU x; x.u = u; return x.h; }

// Row permutation: r' = mt*16 + quad*4 + reg  ->  channel = r'>>2, gate = r'&3.
// orig torch row = gate*Hch + channel. One lane of the C-frag then holds one
// channel's (i,f,g,o) quad (C: col=lane&15, row=(lane>>4)*4+reg).

// Pack W (fp32 [4*Hch][Kdim], torch gate rows) into fp16 A-frag order:
// wp[(mt*KT+kt)*64+lane] = 8 halves of W'[mt*16+(lane&15)][kt*32+(lane>>4)*8+j]
__global__ __launch_bounds__(256) void pack_frag(const float* __restrict__ w,
    uint4* __restrict__ wp, int Hch, int Kdim, int MT, int KT) {
  int o = blockIdx.x * 256 + threadIdx.x;
  if (o >= MT * KT * 64) return;
  int lane = o & 63, fk = o >> 6;
  int kt = fk % KT, mt = fk / KT;
  int rp = mt * 16 + (lane & 15);
  int orig = (rp & 3) * Hch + (rp >> 2);
  int k0 = kt * 32 + (lane >> 4) * 8;
  unsigned r[4];
#pragma unroll
  for (int p = 0; p < 4; ++p) {
    unsigned lo = __half_as_ushort(__float2half_rn(w[(size_t)orig * Kdim + k0 + 2 * p]));
    unsigned hi = __half_as_ushort(__float2half_rn(w[(size_t)orig * Kdim + k0 + 2 * p + 1]));
    r[p] = lo | (hi << 16);
  }
  uint4 v; v.x = r[0]; v.y = r[1]; v.z = r[2]; v.w = r[3];
  wp[o] = v;
}

__global__ __launch_bounds__(256) void pack_bias(const float* __restrict__ bih,
    const float* __restrict__ bhh, float* __restrict__ bs, int Hch) {
  int rp = blockIdx.x * 256 + threadIdx.x;
  if (rp >= 4 * Hch) return;
  int orig = (rp & 3) * Hch + (rp >> 2);
  bs[rp] = bih[orig] + bhh[orig];
}

__global__ void pack_wl(const float* __restrict__ wl, unsigned* __restrict__ wlp, int n) {
  int i = threadIdx.x;
  if (i < n) {
    unsigned lo = __half_as_ushort(__float2half_rn(wl[2 * i]));
    unsigned hi = __half_as_ushort(__float2half_rn(wl[2 * i + 1]));
    wlp[i] = lo | (hi << 16);
  }
}

__global__ __launch_bounds__(256) void f2h(const float* __restrict__ x,
                                           __half* __restrict__ y, int n8) {
  int i = blockIdx.x * 256 + threadIdx.x;
  if (i >= n8) return;
  float4 a = *(const float4*)(x + i * 8);
  float4 b = *(const float4*)(x + i * 8 + 4);
  __half h[8];
  h[0] = __float2half_rn(a.x); h[1] = __float2half_rn(a.y);
  h[2] = __float2half_rn(a.z); h[3] = __float2half_rn(a.w);
  h[4] = __float2half_rn(b.x); h[5] = __float2half_rn(b.y);
  h[6] = __float2half_rn(b.z); h[7] = __float2half_rn(b.w);
  *(uint4*)(y + i * 8) = *(const uint4*)h;
}

// Shared-memory budget: big body needs hb(2x16x264 halves = 16896B) +
// wA(64 m-tiles x 2 kt x 64 lanes x 16B = 131072B) + wls(512B) = 148480B.
// One carved block shared by all three bodies (they never coexist in a WG).
constexpr int HPB = H2 + 8;
constexpr int SM_HB = 2 * 16 * HPB * 2;       // 16896
constexpr int SM_WA = 64 * 2 * 64 * 16;       // 131072
constexpr int SMEM_BYTES = SM_HB + SM_WA + 512;

// L0/L1: one 512-thread WG per 16-batch group, input GEMM fused into the scan
// step (acc = bias + Wih*x(t) + Whh*h(t-1)); weights register-resident;
// double-buffered hb -> ONE barrier/step. (R7-proven body.)
template <int H, int KTI>
DEVINL void scan_small(char* sm, int bt, const __half* __restrict__ x,
    const uint4* __restrict__ wpI, const float* __restrict__ bs,
    const uint4* __restrict__ wp, __half* __restrict__ xout,
    float* __restrict__ sth, float* __restrict__ stc,
    int Sc, int t0, int first) {
  constexpr int MT = H / 4, MTW = MT / 8, KT = H / 32, HP = H + 8, KI = KTI * 32;
  __half* hb0 = (__half*)sm;  // [2][16*HP]
  const int tid = threadIdx.x, w = tid >> 6, lane = tid & 63;
  const int n16 = lane & 15, quad = lane >> 4;
  const int b0 = bt * 16;

  uint4 wih[MTW][KTI];
#pragma unroll
  for (int im = 0; im < MTW; ++im)
#pragma unroll
    for (int kt = 0; kt < KTI; ++kt)
      wih[im][kt] = wpI[((size_t)(w * MTW + im) * KTI + kt) * 64 + lane];
  f32x4 bini[MTW];
#pragma unroll
  for (int im = 0; im < MTW; ++im)
    bini[im] = *(const f32x4*)(bs + (w * MTW + im) * 16 + quad * 4);
  uint4 areg[MTW][KT];
#pragma unroll
  for (int im = 0; im < MTW; ++im)
#pragma unroll
    for (int kt = 0; kt < KT; ++kt)
      areg[im][kt] = wp[((size_t)(w * MTW + im) * KT + kt) * 64 + lane];

  float cst[MTW];
#pragma unroll
  for (int im = 0; im < MTW; ++im) {
    int ch = (w * MTW + im) * 4 + quad;
    cst[im] = first ? 0.f : stc[(size_t)(b0 + n16) * H + ch];
  }
  for (int i = tid; i < 16 * H; i += 512) {
    int n = i / H, ch = i % H;
    hb0[n * HP + ch] = first ? __float2half_rn(0.f)
                             : __float2half_rn(sth[(size_t)(b0 + n) * H + ch]);
  }
  __syncthreads();

  uint4 xcur[KTI];
  {
    const __half* xr = x + ((size_t)(b0 + n16) * S + t0) * KI + quad * 8;
#pragma unroll
    for (int kt = 0; kt < KTI; ++kt) xcur[kt] = *(const uint4*)(xr + kt * 32);
  }

  for (int tl = 0; tl < Sc; ++tl) {
    __half* rb = hb0 + (tl & 1) * 16 * HP;        // h(tl-1)
    __half* wb = hb0 + ((tl + 1) & 1) * 16 * HP;  // receives h(tl)
    const int hid = t0 + tl;

    uint4 xnxt[KTI];
    if (tl + 1 < Sc) {
      const __half* xr = x + ((size_t)(b0 + n16) * S + hid + 1) * KI + quad * 8;
#pragma unroll
      for (int kt = 0; kt < KTI; ++kt) xnxt[kt] = *(const uint4*)(xr + kt * 32);
    }

    f32x4 acc[MTW];
#pragma unroll
    for (int im = 0; im < MTW; ++im) acc[im] = bini[im];
#pragma unroll
    for (int kt = 0; kt < KTI; ++kt)
#pragma unroll
      for (int im = 0; im < MTW; ++im)
        acc[im] = __builtin_amdgcn_mfma_f32_16x16x32_f16(as_f16x8(wih[im][kt]),
                                                         as_f16x8(xcur[kt]), acc[im], 0, 0, 0);

    if (tl > 0) {  // activation emit for h(tl-1), overlaps MFMAs
      if (tid < 16 * (H / 8)) {
        int n = tid / (H / 8), kq = tid % (H / 8);
        uint4 v = *(const uint4*)(rb + n * HP + kq * 8);
        *(uint4*)(xout + ((size_t)(b0 + n) * S + hid - 1) * H + kq * 8) = v;
      }
    }

#pragma unroll
    for (int kt = 0; kt < KT; ++kt) {
      f16x8 bfrag = as_f16x8(*(const uint4*)(rb + n16 * HP + kt * 32 + quad * 8));
#pragma unroll
      for (int im = 0; im < MTW; ++im)
        acc[im] = __builtin_amdgcn_mfma_f32_16x16x32_f16(as_f16x8(areg[im][kt]), bfrag,
                                                         acc[im], 0, 0, 0);
    }

#pragma unroll
    for (int im = 0; im < MTW; ++im) {
      float gi = fsig(acc[im][0]);
      float gf = fsig(acc[im][1]);
      float gg = ftanh_(acc[im][2]);
      float go = fsig(acc[im][3]);
      float cn = gf * cst[im] + gi * gg;
      cst[im] = cn;
      wb[n16 * HP + (w * MTW + im) * 4 + quad] = __float2half_rn(go * ftanh_(cn));
    }
#pragma unroll
    for (int kt = 0; kt < KTI; ++kt) xcur[kt] = xnxt[kt];
    __syncthreads();  // single barrier/step (double-buffered hb)
  }

  __half* fb = hb0 + (Sc & 1) * 16 * HP;
  if (tid < 16 * (H / 8)) {
    int n = tid / (H / 8), kq = tid % (H / 8);
    uint4 v = *(const uint4*)(fb + n * HP + kq * 8);
    *(uint4*)(xout + ((size_t)(b0 + n) * S + t0 + Sc - 1) * H + kq * 8) = v;
  }
  for (int i = tid; i < 16 * H; i += 512) {
    int n = i / H, ch = i % H;
    sth[(size_t)(b0 + n) * H + ch] = __half2float(fb[n * HP + ch]);
  }
#pragma unroll
  for (int im = 0; im < MTW; ++im) {
    int ch = (w * MTW + im) * 4 + quad;
    stc[(size_t)(b0 + n16) * H + ch] = cst[im];
  }
}

// L2: ONE 512-thread WG per batch group — NO cross-WG exchange, no spins.
// Whh hybrid residency: k-tiles 0..5 in registers (192 VGPR/wave), k-tiles
// 6..7 in LDS (128 KB, re-read per step via ds_read_b128). Input GEMM runs as
// an embedded phase -> preT (wih regs die before areg loads; vmcnt(0) pins
// ordering). Scan step: acc=preT load -> 64 MFMAs/wave -> gates -> 1 barrier.
DEVINL void scan_big(char* sm, int bt, const __half* __restrict__ x,
    const uint4* __restrict__ wpI, const float* __restrict__ bs,
    const uint4* __restrict__ wp, f32x4* __restrict__ preT,
    float* __restrict__ out, const unsigned* __restrict__ wlp,
    const float* __restrict__ blp,
    float* __restrict__ sth, float* __restrict__ stc,
    int Sc, int t0, int first) {
  constexpr int H = 256, MT = 64, MTW = 8, KT = 8, KTR = 6, KTI = 4;
  constexpr int HP = H + 8, KI = 128;
  __half* hb0 = (__half*)sm;                    // [2][16*HP]
  uint4* wA = (uint4*)(sm + SM_HB);             // [MT][2][64] k-tiles 6,7
  unsigned* wls = (unsigned*)(sm + SM_HB + SM_WA);
  const int tid = threadIdx.x, w = tid >> 6, lane = tid & 63;
  const int n16 = lane & 15, quad = lane >> 4;
  const int b0 = bt * 16;

  // LDS weight slice fill (kt 6,7) + final-dot weights
  for (int i = tid; i < MT * 2 * 64; i += 512) {
    int mt = i >> 7, r = i & 127, ktl = r >> 6, ln = r & 63;
    wA[i] = wp[((size_t)mt * KT + 6 + ktl) * 64 + ln];
  }
  for (int i = tid; i < H / 2; i += 512) wls[i] = wlp[i];

  // ---- embedded input GEMM phase -> preT (wih regs die before areg) ----
  {
    uint4 wih[MTW][KTI];
#pragma unroll
    for (int im = 0; im < MTW; ++im)
#pragma unroll
      for (int kt = 0; kt < KTI; ++kt)
        wih[im][kt] = wpI[((size_t)(w * MTW + im) * KTI + kt) * 64 + lane];
    f32x4 bini[MTW];
#pragma unroll
    for (int im = 0; im < MTW; ++im)
      bini[im] = *(const f32x4*)(bs + (w * MTW + im) * 16 + quad * 4);
    uint4 bfr[KTI];
    {
      const __half* xr = x + ((size_t)(b0 + n16) * S + t0) * KI + quad * 8;
#pragma unroll
      for (int kt = 0; kt < KTI; ++kt) bfr[kt] = *(const uint4*)(xr + kt * 32);
    }
    for (int t = 0; t < Sc; ++t) {
      uint4 cur[KTI];
#pragma unroll
      for (int kt = 0; kt < KTI; ++kt) cur[kt] = bfr[kt];
      if (t + 1 < Sc) {
        const __half* xr = x + ((size_t)(b0 + n16) * S + t0 + t + 1) * KI + quad * 8;
#pragma unroll
        for (int kt = 0; kt < KTI; ++kt) bfr[kt] = *(const uint4*)(xr + kt * 32);
      }
      f32x4 ac[MTW];
#pragma unroll
      for (int im = 0; im < MTW; ++im) ac[im] = bini[im];
#pragma unroll
      for (int kt = 0; kt < KTI; ++kt)
#pragma unroll
        for (int im = 0; im < MTW; ++im)
          ac[im] = __builtin_amdgcn_mfma_f32_16x16x32_f16(as_f16x8(wih[im][kt]),
                                                          as_f16x8(cur[kt]), ac[im], 0, 0, 0);
#pragma unroll
      for (int im = 0; im < MTW; ++im)
        preT[((size_t)(bt * Sc + t) * MT + w * MTW + im) * 64 + lane] = ac[im];
    }
  }
  asm volatile("s_waitcnt vmcnt(0)" ::: "memory");  // preT visible; pins areg after

  // ---- recurrent weights: k-tiles 0..5 register-resident ----
  uint4 areg[MTW][KTR];
#pragma unroll
  for (int im = 0; im < MTW; ++im)
#pragma unroll
    for (int kt = 0; kt < KTR; ++kt)
      areg[im][kt] = wp[((size_t)(w * MTW + im) * KT + kt) * 64 + lane];

  float cst[MTW];
#pragma unroll
  for (int im = 0; im < MTW; ++im) {
    int ch = (w * MTW + im) * 4 + quad;
    cst[im] = first ? 0.f : stc[(size_t)(b0 + n16) * H + ch];
  }
  for (int i = tid; i < 16 * H; i += 512) {
    int n = i / H, ch = i % H;
    hb0[n * HP + ch] = first ? __float2half_rn(0.f)
                             : __float2half_rn(sth[(size_t)(b0 + n) * H + ch]);
  }
  __syncthreads();  // hb + wA + wls ready

  const float bl0 = blp[0];

  auto emit_out = [&](const __half* rbuf, int t_out) {
    if (tid < 128) {
      int n = tid >> 3, seg = tid & 7;
      const unsigned* hrow = (const unsigned*)(rbuf + n * HP);
      float s = 0.f;
#pragma unroll
      for (int p = 0; p < 16; ++p) s = fdot2(hrow[seg * 16 + p], wls[seg * 16 + p], s);
      s += __shfl_xor(s, 1); s += __shfl_xor(s, 2); s += __shfl_xor(s, 4);
      if (seg == 0) out[(size_t)(b0 + n) * S + t_out] = ftanh_(s + bl0);
    }
  };

  for (int tl = 0; tl < Sc; ++tl) {
    __half* rb = hb0 + (tl & 1) * 16 * HP;        // h(tl-1)
    __half* wb = hb0 + ((tl + 1) & 1) * 16 * HP;  // receives h(tl)

    // acc init = preT(t) (bias + Wih*x already folded in)
    f32x4 acc[MTW];
    {
      const f32x4* pT = preT + ((size_t)(bt * Sc + tl) * MT + w * MTW) * 64 + lane;
#pragma unroll
      for (int im = 0; im < MTW; ++im) acc[im] = pT[im * 64];
    }

    if (tl > 0) emit_out(rb, t0 + tl - 1);  // hides acc-load latency

    // k-tiles 0..5 from registers
#pragma unroll
    for (int kt = 0; kt < KTR; ++kt) {
      f16x8 bfrag = as_f16x8(*(const uint4*)(rb + n16 * HP + kt * 32 + quad * 8));
#pragma unroll
      for (int im = 0; im < MTW; ++im)
        acc[im] = __builtin_amdgcn_mfma_f32_16x16x32_f16(as_f16x8(areg[im][kt]), bfrag,
                                                         acc[im], 0, 0, 0);
    }
    // k-tiles 6..7 from LDS
#pragma unroll
    for (int ktl = 0; ktl < 2; ++ktl) {
      f16x8 bfrag = as_f16x8(*(const uint4*)(rb + n16 * HP + (KTR + ktl) * 32 + quad * 8));
#pragma unroll
      for (int im = 0; im < MTW; ++im) {
        uint4 a = wA[((w * MTW + im) * 2 + ktl) * 64 + lane];
        acc[im] = __builtin_amdgcn_mfma_f32_16x16x32_f16(as_f16x8(a), bfrag,
                                                         acc[im], 0, 0, 0);
      }
    }

#pragma unroll
    for (int im = 0; im < MTW; ++im) {
      float gi = fsig(acc[im][0]);
      float gf = fsig(acc[im][1]);
      float gg = ftanh_(acc[im][2]);
      float go = fsig(acc[im][3]);
      float cn = gf * cst[im] + gi * gg;
      cst[im] = cn;
      wb[n16 * HP + (w * MTW + im) * 4 + quad] = __float2half_rn(go * ftanh_(cn));
    }
    __syncthreads();  // single barrier/step (double-buffered hb)
  }

  __half* fb = hb0 + (Sc & 1) * 16 * HP;
  emit_out(fb, t0 + Sc - 1);

  for (int i = tid; i < 16 * H; i += 512) {
    int n = i / H, ch = i % H;
    sth[(size_t)(b0 + n) * H + ch] = __half2float(fb[n * HP + ch]);
  }
#pragma unroll
  for (int im = 0; im < MTW; ++im) {
    int ch = (w * MTW + im) * 4 + quad;
    stc[(size_t)(b0 + n16) * H + ch] = cst[im];
  }
}

// Fat pipelined kernel: slot s runs L0(chunk s), L1(chunk s-1), L2(chunk s-2)
// as disjoint WG ranges; inter-layer deps carried by dispatch order only.
__global__ __launch_bounds__(512) void scan_fat(
    const __half* x0, __half* x1, __half* x2,
    const uint4* wpI0, const uint4* wpI1, const uint4* wpI2,
    const float* bs0, const float* bs1, const float* bs2,
    const uint4* wpH0, const uint4* wpH1, const uint4* wpH2,
    f32x4* preT2,
    float* out, const unsigned* wlp, const float* blp,
    float* sh0, float* sc0, float* sh1, float* sc1, float* sh2, float* sc2,
    int Sc, int slot, int NC) {
  __shared__ __align__(16) char sm[SMEM_BYTES];
  int b = blockIdx.x;
  if (b < 16) {
    int c = slot;
    if (c >= NC) return;
    scan_small<64, 1>(sm, b, x0, wpI0, bs0, wpH0, x1, sh0, sc0, Sc, c * Sc, c == 0);
  } else if (b < 32) {
    int c = slot - 1;
    if (c < 0 || c >= NC) return;
    scan_small<128, 2>(sm, b - 16, x1, wpI1, bs1, wpH1, x2, sh1, sc1, Sc, c * Sc, c == 0);
  } else {
    int c = slot - 2;
    if (c < 0 || c >= NC) return;
    scan_big(sm, b - 32, x2, wpI2, bs2, wpH2, preT2, out, wlp, blp, sh2, sc2,
             Sc, c * Sc, c == 0);
  }
}

extern "C" void kernel_launch(void* const* d_in, const int* in_sizes, int n_in,
                              void* d_out, int out_size, void* d_ws, size_t ws_size,
                              hipStream_t stream) {
  (void)in_sizes; (void)n_in; (void)out_size;
  const float* noise = (const float*)d_in[0];
  const float* Wih0 = (const float*)d_in[1];
  const float* Whh0 = (const float*)d_in[2];
  const float* bih0 = (const float*)d_in[3];
  const float* bhh0 = (const float*)d_in[4];
  const float* Wih1 = (const float*)d_in[5];
  const float* Whh1 = (const float*)d_in[6];
  const float* bih1 = (const float*)d_in[7];
  const float* bhh1 = (const float*)d_in[8];
  const float* Wih2 = (const float*)d_in[9];
  const float* Whh2 = (const float*)d_in[10];
  const float* bih2 = (const float*)d_in[11];
  const float* bhh2 = (const float*)d_in[12];
  const float* Wl = (const float*)d_in[13];
  const float* bl = (const float*)d_in[14];
  float* out = (float*)d_out;

  char* p = (char*)d_ws;
  auto alloc = [&](size_t bytes) {
    char* r = p;
    p += (bytes + 255) & ~(size_t)255;
    return r;
  };
  // A-frag packed weights (fp16): recurrent + input
  uint4* wpH0 = (uint4*)alloc((size_t)16 * 2 * 1024);
  uint4* wpH1 = (uint4*)alloc((size_t)32 * 4 * 1024);
  uint4* wpH2 = (uint4*)alloc((size_t)64 * 8 * 1024);
  uint4* wpI0 = (uint4*)alloc((size_t)16 * 1 * 1024);
  uint4* wpI1 = (uint4*)alloc((size_t)32 * 2 * 1024);
  uint4* wpI2 = (uint4*)alloc((size_t)64 * 4 * 1024);
  float* bs0 = (float*)alloc(256 * 4);
  float* bs1 = (float*)alloc(512 * 4);
  float* bs2 = (float*)alloc(1024 * 4);
  unsigned* wlp = (unsigned*)alloc(128 * 4);
  // state carry
  float* sh0 = (float*)alloc((size_t)B * H0 * 4);
  float* sc0 = (float*)alloc((size_t)B * H0 * 4);
  float* sh1 = (float*)alloc((size_t)B * H1 * 4);
  float* sc1 = (float*)alloc((size_t)B * H1 * 4);
  float* sh2 = (float*)alloc((size_t)B * H2 * 4);
  float* sc2 = (float*)alloc((size_t)B * H2 * 4);
  // activations (fp16)
  __half* x0 = (__half*)alloc((size_t)B * S * 32 * 2);
  __half* x1 = (__half*)alloc((size_t)B * S * H0 * 2);
  __half* x2 = (__half*)alloc((size_t)B * S * H1 * 2);
  size_t fixed = (size_t)(p - (char*)d_ws);
  int Sc = 64;  // chunk size; preT2 holds one chunk (L2 only)
  while (Sc > 16 && fixed + (size_t)B * Sc * 16 * H2 > ws_size) Sc >>= 1;
  f32x4* preT2 = (f32x4*)alloc((size_t)B * Sc * 16 * H2);

  // ---- packing (every call; deterministic) ----
  pack_frag<<<(16 * 2 * 64 + 255) / 256, 256, 0, stream>>>(Whh0, wpH0, 64, 64, 16, 2);
  pack_frag<<<(32 * 4 * 64 + 255) / 256, 256, 0, stream>>>(Whh1, wpH1, 128, 128, 32, 4);
  pack_frag<<<(64 * 8 * 64 + 255) / 256, 256, 0, stream>>>(Whh2, wpH2, 256, 256, 64, 8);
  pack_frag<<<(16 * 1 * 64 + 255) / 256, 256, 0, stream>>>(Wih0, wpI0, 64, 32, 16, 1);
  pack_frag<<<(32 * 2 * 64 + 255) / 256, 256, 0, stream>>>(Wih1, wpI1, 128, 64, 32, 2);
  pack_frag<<<(64 * 4 * 64 + 255) / 256, 256, 0, stream>>>(Wih2, wpI2, 256, 128, 64, 4);
  pack_bias<<<1, 256, 0, stream>>>(bih0, bhh0, bs0, 64);
  pack_bias<<<2, 256, 0, stream>>>(bih1, bhh1, bs1, 128);
  pack_bias<<<4, 256, 0, stream>>>(bih2, bhh2, bs2, 256);
  pack_wl<<<1, 128, 0, stream>>>(Wl, wlp, 128);
  f2h<<<(B * S * 32 / 8 + 255) / 256, 256, 0, stream>>>(noise, x0, B * S * 32 / 8);

  // ---- pipelined slots: L0(c=s) || L1(c=s-1) || L2(c=s-2) ----
  int NC = S / Sc;
  for (int slot = 0; slot < NC + 2; ++slot)
    scan_fat<<<48, 512, 0, stream>>>(x0, x1, x2, wpI0, wpI1, wpI2, bs0, bs1, bs2,
                                     wpH0, wpH1, wpH2, preT2,
                                     out, wlp, bl, sh0, sc0, sh1, sc1, sh2, sc2,
                                     Sc, slot, NC);
}

// Round 11
// 3275.436 us; speedup vs baseline: 1.0007x; 1.0007x over previous
//
#include <hip/hip_runtime.h>
#include <hip/hip_fp16.h>

#define DEVINL __device__ __forceinline__

constexpr int B = 256, S = 512;
constexpr int H0 = 64, H1 = 128, H2 = 256;

typedef _Float16 f16x8 __attribute__((ext_vector_type(8)));
typedef float f32x4 __attribute__((ext_vector_type(4)));
typedef _Float16 h2v __attribute__((ext_vector_type(2)));

DEVINL float fexp2(float x) { return __builtin_amdgcn_exp2f(x); }
DEVINL float frcp(float x) { return __builtin_amdgcn_rcpf(x); }
DEVINL float fsig(float x) { return frcp(1.f + fexp2(-1.44269504088896f * x)); }
DEVINL float ftanh_(float x) { return 1.f - 2.f * frcp(1.f + fexp2(2.88539008177793f * x)); }
DEVINL h2v as_h2(unsigned u) { union { unsigned u; h2v h; } x; x.u = u; return x.h; }
DEVINL float fdot2(unsigned a, unsigned b, float c) {
  return __builtin_amdgcn_fdot2(as_h2(a), as_h2(b), c, false);
}
union FU { uint4 u; f16x8 h; };
DEVINL f16x8 as_f16x8(uint4 u) { FU x; x.u = u; return x.h; }

// Row permutation: r' = mt*16 + quad*4 + reg  ->  channel = r'>>2, gate = r'&3.
// orig torch row = gate*Hch + channel. One lane of the C-frag then holds one
// channel's (i,f,g,o) quad (C: col=lane&15, row=(lane>>4)*4+reg).

// Pack W (fp32 [4*Hch][Kdim], torch gate rows) into fp16 A-frag order:
// wp[(mt*KT+kt)*64+lane] = 8 halves of W'[mt*16+(lane&15)][kt*32+(lane>>4)*8+j]
__global__ __launch_bounds__(256) void pack_frag(const float* __restrict__ w,
    uint4* __restrict__ wp, int Hch, int Kdim, int MT, int KT) {
  int o = blockIdx.x * 256 + threadIdx.x;
  if (o >= MT * KT * 64) return;
  int lane = o & 63, fk = o >> 6;
  int kt = fk % KT, mt = fk / KT;
  int rp = mt * 16 + (lane & 15);
  int orig = (rp & 3) * Hch + (rp >> 2);
  int k0 = kt * 32 + (lane >> 4) * 8;
  unsigned r[4];
#pragma unroll
  for (int p = 0; p < 4; ++p) {
    unsigned lo = __half_as_ushort(__float2half_rn(w[(size_t)orig * Kdim + k0 + 2 * p]));
    unsigned hi = __half_as_ushort(__float2half_rn(w[(size_t)orig * Kdim + k0 + 2 * p + 1]));
    r[p] = lo | (hi << 16);
  }
  uint4 v; v.x = r[0]; v.y = r[1]; v.z = r[2]; v.w = r[3];
  wp[o] = v;
}

__global__ __launch_bounds__(256) void pack_bias(const float* __restrict__ bih,
    const float* __restrict__ bhh, float* __restrict__ bs, int Hch) {
  int rp = blockIdx.x * 256 + threadIdx.x;
  if (rp >= 4 * Hch) return;
  int orig = (rp & 3) * Hch + (rp >> 2);
  bs[rp] = bih[orig] + bhh[orig];
}

__global__ void pack_wl(const float* __restrict__ wl, unsigned* __restrict__ wlp, int n) {
  int i = threadIdx.x;
  if (i < n) {
    unsigned lo = __half_as_ushort(__float2half_rn(wl[2 * i]));
    unsigned hi = __half_as_ushort(__float2half_rn(wl[2 * i + 1]));
    wlp[i] = lo | (hi << 16);
  }
}

__global__ __launch_bounds__(256) void f2h(const float* __restrict__ x,
                                           __half* __restrict__ y, int n8) {
  int i = blockIdx.x * 256 + threadIdx.x;
  if (i >= n8) return;
  float4 a = *(const float4*)(x + i * 8);
  float4 b = *(const float4*)(x + i * 8 + 4);
  __half h[8];
  h[0] = __float2half_rn(a.x); h[1] = __float2half_rn(a.y);
  h[2] = __float2half_rn(a.z); h[3] = __float2half_rn(a.w);
  h[4] = __float2half_rn(b.x); h[5] = __float2half_rn(b.y);
  h[6] = __float2half_rn(b.z); h[7] = __float2half_rn(b.w);
  *(uint4*)(y + i * 8) = *(const uint4*)h;
}

// Shared-memory budget: big body needs hb(2x16x264 halves = 16896B) +
// wA(64 m-tiles x 2 kt x 64 lanes x 16B = 131072B) + wls(512B) = 148480B.
// One carved block shared by all three bodies (they never coexist in a WG).
// LDS pins occupancy at 1 WG/CU = 2 waves/SIMD -> 256 VGPRs/wave are legal;
// __launch_bounds__(512, 2) on scan_fat tells the allocator to use them
// (R10's missing declaration -> 128-reg budget -> weight spills, 2x slower).
constexpr int HPB = H2 + 8;
constexpr int SM_HB = 2 * 16 * HPB * 2;       // 16896
constexpr int SM_WA = 64 * 2 * 64 * 16;       // 131072
constexpr int SMEM_BYTES = SM_HB + SM_WA + 512;

// L0/L1: one 512-thread WG per 16-batch group, input GEMM fused into the scan
// step (acc = bias + Wih*x(t) + Whh*h(t-1)); weights register-resident;
// double-buffered hb -> ONE barrier/step. (R7-proven body.)
template <int H, int KTI>
DEVINL void scan_small(char* sm, int bt, const __half* __restrict__ x,
    const uint4* __restrict__ wpI, const float* __restrict__ bs,
    const uint4* __restrict__ wp, __half* __restrict__ xout,
    float* __restrict__ sth, float* __restrict__ stc,
    int Sc, int t0, int first) {
  constexpr int MT = H / 4, MTW = MT / 8, KT = H / 32, HP = H + 8, KI = KTI * 32;
  __half* hb0 = (__half*)sm;  // [2][16*HP]
  const int tid = threadIdx.x, w = tid >> 6, lane = tid & 63;
  const int n16 = lane & 15, quad = lane >> 4;
  const int b0 = bt * 16;

  uint4 wih[MTW][KTI];
#pragma unroll
  for (int im = 0; im < MTW; ++im)
#pragma unroll
    for (int kt = 0; kt < KTI; ++kt)
      wih[im][kt] = wpI[((size_t)(w * MTW + im) * KTI + kt) * 64 + lane];
  f32x4 bini[MTW];
#pragma unroll
  for (int im = 0; im < MTW; ++im)
    bini[im] = *(const f32x4*)(bs + (w * MTW + im) * 16 + quad * 4);
  uint4 areg[MTW][KT];
#pragma unroll
  for (int im = 0; im < MTW; ++im)
#pragma unroll
    for (int kt = 0; kt < KT; ++kt)
      areg[im][kt] = wp[((size_t)(w * MTW + im) * KT + kt) * 64 + lane];

  float cst[MTW];
#pragma unroll
  for (int im = 0; im < MTW; ++im) {
    int ch = (w * MTW + im) * 4 + quad;
    cst[im] = first ? 0.f : stc[(size_t)(b0 + n16) * H + ch];
  }
  for (int i = tid; i < 16 * H; i += 512) {
    int n = i / H, ch = i % H;
    hb0[n * HP + ch] = first ? __float2half_rn(0.f)
                             : __float2half_rn(sth[(size_t)(b0 + n) * H + ch]);
  }
  __syncthreads();

  uint4 xcur[KTI];
  {
    const __half* xr = x + ((size_t)(b0 + n16) * S + t0) * KI + quad * 8;
#pragma unroll
    for (int kt = 0; kt < KTI; ++kt) xcur[kt] = *(const uint4*)(xr + kt * 32);
  }

  for (int tl = 0; tl < Sc; ++tl) {
    __half* rb = hb0 + (tl & 1) * 16 * HP;        // h(tl-1)
    __half* wb = hb0 + ((tl + 1) & 1) * 16 * HP;  // receives h(tl)
    const int hid = t0 + tl;

    uint4 xnxt[KTI];
    if (tl + 1 < Sc) {
      const __half* xr = x + ((size_t)(b0 + n16) * S + hid + 1) * KI + quad * 8;
#pragma unroll
      for (int kt = 0; kt < KTI; ++kt) xnxt[kt] = *(const uint4*)(xr + kt * 32);
    }

    f32x4 acc[MTW];
#pragma unroll
    for (int im = 0; im < MTW; ++im) acc[im] = bini[im];
#pragma unroll
    for (int kt = 0; kt < KTI; ++kt)
#pragma unroll
      for (int im = 0; im < MTW; ++im)
        acc[im] = __builtin_amdgcn_mfma_f32_16x16x32_f16(as_f16x8(wih[im][kt]),
                                                         as_f16x8(xcur[kt]), acc[im], 0, 0, 0);

    if (tl > 0) {  // activation emit for h(tl-1), overlaps MFMAs
      if (tid < 16 * (H / 8)) {
        int n = tid / (H / 8), kq = tid % (H / 8);
        uint4 v = *(const uint4*)(rb + n * HP + kq * 8);
        *(uint4*)(xout + ((size_t)(b0 + n) * S + hid - 1) * H + kq * 8) = v;
      }
    }

#pragma unroll
    for (int kt = 0; kt < KT; ++kt) {
      f16x8 bfrag = as_f16x8(*(const uint4*)(rb + n16 * HP + kt * 32 + quad * 8));
#pragma unroll
      for (int im = 0; im < MTW; ++im)
        acc[im] = __builtin_amdgcn_mfma_f32_16x16x32_f16(as_f16x8(areg[im][kt]), bfrag,
                                                         acc[im], 0, 0, 0);
    }

#pragma unroll
    for (int im = 0; im < MTW; ++im) {
      float gi = fsig(acc[im][0]);
      float gf = fsig(acc[im][1]);
      float gg = ftanh_(acc[im][2]);
      float go = fsig(acc[im][3]);
      float cn = gf * cst[im] + gi * gg;
      cst[im] = cn;
      wb[n16 * HP + (w * MTW + im) * 4 + quad] = __float2half_rn(go * ftanh_(cn));
    }
#pragma unroll
    for (int kt = 0; kt < KTI; ++kt) xcur[kt] = xnxt[kt];
    __syncthreads();  // single barrier/step (double-buffered hb)
  }

  __half* fb = hb0 + (Sc & 1) * 16 * HP;
  if (tid < 16 * (H / 8)) {
    int n = tid / (H / 8), kq = tid % (H / 8);
    uint4 v = *(const uint4*)(fb + n * HP + kq * 8);
    *(uint4*)(xout + ((size_t)(b0 + n) * S + t0 + Sc - 1) * H + kq * 8) = v;
  }
  for (int i = tid; i < 16 * H; i += 512) {
    int n = i / H, ch = i % H;
    sth[(size_t)(b0 + n) * H + ch] = __half2float(fb[n * HP + ch]);
  }
#pragma unroll
  for (int im = 0; im < MTW; ++im) {
    int ch = (w * MTW + im) * 4 + quad;
    stc[(size_t)(b0 + n16) * H + ch] = cst[im];
  }
}

// L2: ONE 512-thread WG per batch group — NO cross-WG exchange, no spins.
// Whh hybrid residency: k-tiles 0..5 in registers (192 VGPR/wave), k-tiles
// 6..7 in LDS (128 KB, re-read per step via ds_read_b128). Input GEMM runs as
// an embedded phase -> preT (wih regs die before areg loads; vmcnt(0) pins
// ordering). Scan step: acc=preT load -> 64 MFMAs/wave -> gates -> 1 barrier.
DEVINL void scan_big(char* sm, int bt, const __half* __restrict__ x,
    const uint4* __restrict__ wpI, const float* __restrict__ bs,
    const uint4* __restrict__ wp, f32x4* __restrict__ preT,
    float* __restrict__ out, const unsigned* __restrict__ wlp,
    const float* __restrict__ blp,
    float* __restrict__ sth, float* __restrict__ stc,
    int Sc, int t0, int first) {
  constexpr int H = 256, MT = 64, MTW = 8, KT = 8, KTR = 6, KTI = 4;
  constexpr int HP = H + 8, KI = 128;
  __half* hb0 = (__half*)sm;                    // [2][16*HP]
  uint4* wA = (uint4*)(sm + SM_HB);             // [MT][2][64] k-tiles 6,7
  unsigned* wls = (unsigned*)(sm + SM_HB + SM_WA);
  const int tid = threadIdx.x, w = tid >> 6, lane = tid & 63;
  const int n16 = lane & 15, quad = lane >> 4;
  const int b0 = bt * 16;

  // LDS weight slice fill (kt 6,7) + final-dot weights
  for (int i = tid; i < MT * 2 * 64; i += 512) {
    int mt = i >> 7, r = i & 127, ktl = r >> 6, ln = r & 63;
    wA[i] = wp[((size_t)mt * KT + 6 + ktl) * 64 + ln];
  }
  for (int i = tid; i < H / 2; i += 512) wls[i] = wlp[i];

  // ---- embedded input GEMM phase -> preT (wih regs die before areg) ----
  {
    uint4 wih[MTW][KTI];
#pragma unroll
    for (int im = 0; im < MTW; ++im)
#pragma unroll
      for (int kt = 0; kt < KTI; ++kt)
        wih[im][kt] = wpI[((size_t)(w * MTW + im) * KTI + kt) * 64 + lane];
    f32x4 bini[MTW];
#pragma unroll
    for (int im = 0; im < MTW; ++im)
      bini[im] = *(const f32x4*)(bs + (w * MTW + im) * 16 + quad * 4);
    uint4 bfr[KTI];
    {
      const __half* xr = x + ((size_t)(b0 + n16) * S + t0) * KI + quad * 8;
#pragma unroll
      for (int kt = 0; kt < KTI; ++kt) bfr[kt] = *(const uint4*)(xr + kt * 32);
    }
    for (int t = 0; t < Sc; ++t) {
      uint4 cur[KTI];
#pragma unroll
      for (int kt = 0; kt < KTI; ++kt) cur[kt] = bfr[kt];
      if (t + 1 < Sc) {
        const __half* xr = x + ((size_t)(b0 + n16) * S + t0 + t + 1) * KI + quad * 8;
#pragma unroll
        for (int kt = 0; kt < KTI; ++kt) bfr[kt] = *(const uint4*)(xr + kt * 32);
      }
      f32x4 ac[MTW];
#pragma unroll
      for (int im = 0; im < MTW; ++im) ac[im] = bini[im];
#pragma unroll
      for (int kt = 0; kt < KTI; ++kt)
#pragma unroll
        for (int im = 0; im < MTW; ++im)
          ac[im] = __builtin_amdgcn_mfma_f32_16x16x32_f16(as_f16x8(wih[im][kt]),
                                                          as_f16x8(cur[kt]), ac[im], 0, 0, 0);
#pragma unroll
      for (int im = 0; im < MTW; ++im)
        preT[((size_t)(bt * Sc + t) * MT + w * MTW + im) * 64 + lane] = ac[im];
    }
  }
  asm volatile("s_waitcnt vmcnt(0)" ::: "memory");  // preT visible; pins areg after

  // ---- recurrent weights: k-tiles 0..5 register-resident ----
  uint4 areg[MTW][KTR];
#pragma unroll
  for (int im = 0; im < MTW; ++im)
#pragma unroll
    for (int kt = 0; kt < KTR; ++kt)
      areg[im][kt] = wp[((size_t)(w * MTW + im) * KT + kt) * 64 + lane];

  float cst[MTW];
#pragma unroll
  for (int im = 0; im < MTW; ++im) {
    int ch = (w * MTW + im) * 4 + quad;
    cst[im] = first ? 0.f : stc[(size_t)(b0 + n16) * H + ch];
  }
  for (int i = tid; i < 16 * H; i += 512) {
    int n = i / H, ch = i % H;
    hb0[n * HP + ch] = first ? __float2half_rn(0.f)
                             : __float2half_rn(sth[(size_t)(b0 + n) * H + ch]);
  }
  __syncthreads();  // hb + wA + wls ready

  const float bl0 = blp[0];

  auto emit_out = [&](const __half* rbuf, int t_out) {
    if (tid < 128) {
      int n = tid >> 3, seg = tid & 7;
      const unsigned* hrow = (const unsigned*)(rbuf + n * HP);
      float s = 0.f;
#pragma unroll
      for (int p = 0; p < 16; ++p) s = fdot2(hrow[seg * 16 + p], wls[seg * 16 + p], s);
      s += __shfl_xor(s, 1); s += __shfl_xor(s, 2); s += __shfl_xor(s, 4);
      if (seg == 0) out[(size_t)(b0 + n) * S + t_out] = ftanh_(s + bl0);
    }
  };

  for (int tl = 0; tl < Sc; ++tl) {
    __half* rb = hb0 + (tl & 1) * 16 * HP;        // h(tl-1)
    __half* wb = hb0 + ((tl + 1) & 1) * 16 * HP;  // receives h(tl)

    // acc init = preT(t) (bias + Wih*x already folded in)
    f32x4 acc[MTW];
    {
      const f32x4* pT = preT + ((size_t)(bt * Sc + tl) * MT + w * MTW) * 64 + lane;
#pragma unroll
      for (int im = 0; im < MTW; ++im) acc[im] = pT[im * 64];
    }

    if (tl > 0) emit_out(rb, t0 + tl - 1);  // hides acc-load latency

    // k-tiles 0..5 from registers
#pragma unroll
    for (int kt = 0; kt < KTR; ++kt) {
      f16x8 bfrag = as_f16x8(*(const uint4*)(rb + n16 * HP + kt * 32 + quad * 8));
#pragma unroll
      for (int im = 0; im < MTW; ++im)
        acc[im] = __builtin_amdgcn_mfma_f32_16x16x32_f16(as_f16x8(areg[im][kt]), bfrag,
                                                         acc[im], 0, 0, 0);
    }
    // k-tiles 6..7 from LDS
#pragma unroll
    for (int ktl = 0; ktl < 2; ++ktl) {
      f16x8 bfrag = as_f16x8(*(const uint4*)(rb + n16 * HP + (KTR + ktl) * 32 + quad * 8));
#pragma unroll
      for (int im = 0; im < MTW; ++im) {
        uint4 a = wA[((w * MTW + im) * 2 + ktl) * 64 + lane];
        acc[im] = __builtin_amdgcn_mfma_f32_16x16x32_f16(as_f16x8(a), bfrag,
                                                         acc[im], 0, 0, 0);
      }
    }

#pragma unroll
    for (int im = 0; im < MTW; ++im) {
      float gi = fsig(acc[im][0]);
      float gf = fsig(acc[im][1]);
      float gg = ftanh_(acc[im][2]);
      float go = fsig(acc[im][3]);
      float cn = gf * cst[im] + gi * gg;
      cst[im] = cn;
      wb[n16 * HP + (w * MTW + im) * 4 + quad] = __float2half_rn(go * ftanh_(cn));
    }
    __syncthreads();  // single barrier/step (double-buffered hb)
  }

  __half* fb = hb0 + (Sc & 1) * 16 * HP;
  emit_out(fb, t0 + Sc - 1);

  for (int i = tid; i < 16 * H; i += 512) {
    int n = i / H, ch = i % H;
    sth[(size_t)(b0 + n) * H + ch] = __half2float(fb[n * HP + ch]);
  }
#pragma unroll
  for (int im = 0; im < MTW; ++im) {
    int ch = (w * MTW + im) * 4 + quad;
    stc[(size_t)(b0 + n16) * H + ch] = cst[im];
  }
}

// Fat pipelined kernel: slot s runs L0(chunk s), L1(chunk s-1), L2(chunk s-2)
// as disjoint WG ranges; inter-layer deps carried by dispatch order only.
// __launch_bounds__(512, 2): min 2 waves/EU -> VGPR cap 256/wave, which the
// big body's 192-reg weight set + 32-reg acc needs. (R10 defaulted to 128 and
// spilled the weights to scratch -> 2x regression.)
__global__ __launch_bounds__(512, 2) void scan_fat(
    const __half* x0, __half* x1, __half* x2,
    const uint4* wpI0, const uint4* wpI1, const uint4* wpI2,
    const float* bs0, const float* bs1, const float* bs2,
    const uint4* wpH0, const uint4* wpH1, const uint4* wpH2,
    f32x4* preT2,
    float* out, const unsigned* wlp, const float* blp,
    float* sh0, float* sc0, float* sh1, float* sc1, float* sh2, float* sc2,
    int Sc, int slot, int NC) {
  __shared__ __align__(16) char sm[SMEM_BYTES];
  int b = blockIdx.x;
  if (b < 16) {
    int c = slot;
    if (c >= NC) return;
    scan_small<64, 1>(sm, b, x0, wpI0, bs0, wpH0, x1, sh0, sc0, Sc, c * Sc, c == 0);
  } else if (b < 32) {
    int c = slot - 1;
    if (c < 0 || c >= NC) return;
    scan_small<128, 2>(sm, b - 16, x1, wpI1, bs1, wpH1, x2, sh1, sc1, Sc, c * Sc, c == 0);
  } else {
    int c = slot - 2;
    if (c < 0 || c >= NC) return;
    scan_big(sm, b - 32, x2, wpI2, bs2, wpH2, preT2, out, wlp, blp, sh2, sc2,
             Sc, c * Sc, c == 0);
  }
}

extern "C" void kernel_launch(void* const* d_in, const int* in_sizes, int n_in,
                              void* d_out, int out_size, void* d_ws, size_t ws_size,
                              hipStream_t stream) {
  (void)in_sizes; (void)n_in; (void)out_size;
  const float* noise = (const float*)d_in[0];
  const float* Wih0 = (const float*)d_in[1];
  const float* Whh0 = (const float*)d_in[2];
  const float* bih0 = (const float*)d_in[3];
  const float* bhh0 = (const float*)d_in[4];
  const float* Wih1 = (const float*)d_in[5];
  const float* Whh1 = (const float*)d_in[6];
  const float* bih1 = (const float*)d_in[7];
  const float* bhh1 = (const float*)d_in[8];
  const float* Wih2 = (const float*)d_in[9];
  const float* Whh2 = (const float*)d_in[10];
  const float* bih2 = (const float*)d_in[11];
  const float* bhh2 = (const float*)d_in[12];
  const float* Wl = (const float*)d_in[13];
  const float* bl = (const float*)d_in[14];
  float* out = (float*)d_out;

  char* p = (char*)d_ws;
  auto alloc = [&](size_t bytes) {
    char* r = p;
    p += (bytes + 255) & ~(size_t)255;
    return r;
  };
  // A-frag packed weights (fp16): recurrent + input
  uint4* wpH0 = (uint4*)alloc((size_t)16 * 2 * 1024);
  uint4* wpH1 = (uint4*)alloc((size_t)32 * 4 * 1024);
  uint4* wpH2 = (uint4*)alloc((size_t)64 * 8 * 1024);
  uint4* wpI0 = (uint4*)alloc((size_t)16 * 1 * 1024);
  uint4* wpI1 = (uint4*)alloc((size_t)32 * 2 * 1024);
  uint4* wpI2 = (uint4*)alloc((size_t)64 * 4 * 1024);
  float* bs0 = (float*)alloc(256 * 4);
  float* bs1 = (float*)alloc(512 * 4);
  float* bs2 = (float*)alloc(1024 * 4);
  unsigned* wlp = (unsigned*)alloc(128 * 4);
  // state carry
  float* sh0 = (float*)alloc((size_t)B * H0 * 4);
  float* sc0 = (float*)alloc((size_t)B * H0 * 4);
  float* sh1 = (float*)alloc((size_t)B * H1 * 4);
  float* sc1 = (float*)alloc((size_t)B * H1 * 4);
  float* sh2 = (float*)alloc((size_t)B * H2 * 4);
  float* sc2 = (float*)alloc((size_t)B * H2 * 4);
  // activations (fp16)
  __half* x0 = (__half*)alloc((size_t)B * S * 32 * 2);
  __half* x1 = (__half*)alloc((size_t)B * S * H0 * 2);
  __half* x2 = (__half*)alloc((size_t)B * S * H1 * 2);
  size_t fixed = (size_t)(p - (char*)d_ws);
  int Sc = 64;  // chunk size; preT2 holds one chunk (L2 only)
  while (Sc > 16 && fixed + (size_t)B * Sc * 16 * H2 > ws_size) Sc >>= 1;
  f32x4* preT2 = (f32x4*)alloc((size_t)B * Sc * 16 * H2);

  // ---- packing (every call; deterministic) ----
  pack_frag<<<(16 * 2 * 64 + 255) / 256, 256, 0, stream>>>(Whh0, wpH0, 64, 64, 16, 2);
  pack_frag<<<(32 * 4 * 64 + 255) / 256, 256, 0, stream>>>(Whh1, wpH1, 128, 128, 32, 4);
  pack_frag<<<(64 * 8 * 64 + 255) / 256, 256, 0, stream>>>(Whh2, wpH2, 256, 256, 64, 8);
  pack_frag<<<(16 * 1 * 64 + 255) / 256, 256, 0, stream>>>(Wih0, wpI0, 64, 32, 16, 1);
  pack_frag<<<(32 * 2 * 64 + 255) / 256, 256, 0, stream>>>(Wih1, wpI1, 128, 64, 32, 2);
  pack_frag<<<(64 * 4 * 64 + 255) / 256, 256, 0, stream>>>(Wih2, wpI2, 256, 128, 64, 4);
  pack_bias<<<1, 256, 0, stream>>>(bih0, bhh0, bs0, 64);
  pack_bias<<<2, 256, 0, stream>>>(bih1, bhh1, bs1, 128);
  pack_bias<<<4, 256, 0, stream>>>(bih2, bhh2, bs2, 256);
  pack_wl<<<1, 128, 0, stream>>>(Wl, wlp, 128);
  f2h<<<(B * S * 32 / 8 + 255) / 256, 256, 0, stream>>>(noise, x0, B * S * 32 / 8);

  // ---- pipelined slots: L0(c=s) || L1(c=s-1) || L2(c=s-2) ----
  int NC = S / Sc;
  for (int slot = 0; slot < NC + 2; ++slot)
    scan_fat<<<48, 512, 0, stream>>>(x0, x1, x2, wpI0, wpI1, wpI2, bs0, bs1, bs2,
                                     wpH0, wpH1, wpH2, preT2,
                                     out, wlp, bl, sh0, sc0, sh1, sc1, sh2, sc2,
                                     Sc, slot, NC);
}